// Round 1
// baseline (1317.829 us; speedup 1.0000x reference)
//
#include <hip/hip_runtime.h>
#include <math.h>

#define DMODEL 1024
#define NHEAD  16
#define HDK    64
#define BATCH  2
#define SEQ    2048
#define MROWS  (BATCH*SEQ)   // 4096
#define NQKV   (3*DMODEL)    // 3072

// log2(10000)
#define LOG2_10000 13.287712379549449f

// ---------------------------------------------------------------------------
// Kernel A: qkv = x @ W_qkv + b_qkv, fused RoPE (q,k) + transpose to (B,H,T,DK)
// grid (NQKV/64, MROWS/64), block 256 (16x16 threads, 4x4 microtile)
// ---------------------------------------------------------------------------
__global__ __launch_bounds__(256) void qkv_rope_kernel(
    const float* __restrict__ x, const float* __restrict__ W,
    const float* __restrict__ bias,
    float* __restrict__ qd, float* __restrict__ kd, float* __restrict__ vd)
{
    __shared__ float As[16][64];   // [k][m]
    __shared__ float Bs[16][64];   // [k][n]
    const int tid = threadIdx.x;
    const int tx = tid & 15, ty = tid >> 4;
    const int n0 = blockIdx.x * 64;
    const int m0 = blockIdx.y * 64;
    float acc[4][4] = {};

    for (int k0 = 0; k0 < DMODEL; k0 += 16) {
        const int e = tid * 4;
        const int arow = e >> 4, akk = e & 15;     // A: 64 rows x 16 k
        const float4 av = *(const float4*)(x + (size_t)(m0 + arow) * DMODEL + k0 + akk);
        const int bkk = e >> 6, bcol = e & 63;     // B: 16 k x 64 n
        const float4 bv = *(const float4*)(W + (size_t)(k0 + bkk) * NQKV + n0 + bcol);
        __syncthreads();   // previous iteration's reads done before overwrite
        As[akk+0][arow] = av.x; As[akk+1][arow] = av.y;
        As[akk+2][arow] = av.z; As[akk+3][arow] = av.w;
        *(float4*)&Bs[bkk][bcol] = bv;
        __syncthreads();
        #pragma unroll
        for (int kk = 0; kk < 16; ++kk) {
            float a[4], bb[4];
            #pragma unroll
            for (int i = 0; i < 4; ++i) a[i]  = As[kk][ty*4+i];
            #pragma unroll
            for (int j = 0; j < 4; ++j) bb[j] = Bs[kk][tx*4+j];
            #pragma unroll
            for (int i = 0; i < 4; ++i)
                #pragma unroll
                for (int j = 0; j < 4; ++j)
                    acc[i][j] += a[i]*bb[j];
        }
    }

    // epilogue: bias + rope + scatter to (B,H,T,DK)
    const int nbase = n0 + tx*4;
    const int which = nbase >> 10;        // 0=q 1=k 2=v
    const int rem   = nbase & 1023;
    const int h     = rem >> 6;
    const int dbase = rem & 63;           // multiple of 4 -> pairs stay in-thread
    float* dst = (which == 0) ? qd : (which == 1) ? kd : vd;
    const float b0 = bias[nbase+0], b1 = bias[nbase+1];
    const float b2 = bias[nbase+2], b3 = bias[nbase+3];
    const int jj0 = dbase >> 1;
    const float invf0 = exp2f(-((float)(2*jj0)     / 64.f) * LOG2_10000);
    const float invf1 = exp2f(-((float)(2*(jj0+1)) / 64.f) * LOG2_10000);

    #pragma unroll
    for (int i = 0; i < 4; ++i) {
        const int m = m0 + ty*4 + i;
        const int b = m >> 11;            // / SEQ
        const int t = m & (SEQ-1);
        float v0 = acc[i][0] + b0, v1 = acc[i][1] + b1;
        float v2 = acc[i][2] + b2, v3 = acc[i][3] + b3;
        float* p = dst + (((size_t)(b*NHEAD + h) * SEQ + t) * HDK + dbase);
        if (which < 2) {
            const float tf = (float)t;
            const float a0 = tf * invf0, a1 = tf * invf1;
            const float c0 = cosf(a0), s0 = sinf(a0);
            const float c1 = cosf(a1), s1 = sinf(a1);
            p[0] = v0*c0 - v1*s0;
            p[1] = v0*s0 + v1*c0;
            p[2] = v2*c1 - v3*s1;
            p[3] = v2*s1 + v3*c1;
        } else {
            p[0] = v0; p[1] = v1; p[2] = v2; p[3] = v3;
        }
    }
}

// ---------------------------------------------------------------------------
// Kernel B: flash-style causal attention, fp32.
// grid (SEQ/32, NHEAD, BATCH), block 256.
// Q-tile 32 rows; K/V tiles 64 rows; online softmax.
// Output written as (B, T, H, DK) == (B*T, D) row-major for the out-GEMM.
// ---------------------------------------------------------------------------
__global__ __launch_bounds__(256) void attn_kernel(
    const float* __restrict__ qd, const float* __restrict__ kd,
    const float* __restrict__ vd, float* __restrict__ od)
{
    __shared__ float Qs[32][65];
    __shared__ float Ks[64][65];
    __shared__ float Vs[64][64];
    __shared__ float Ss[32][65];
    __shared__ float mrow[32], lrow[32], arow[32];

    const int tid = threadIdx.x;
    const int tx = tid & 15, ty = tid >> 4;
    const int q0 = blockIdx.x * 32;
    const int h = blockIdx.y, b = blockIdx.z;
    const size_t base = ((size_t)(b*NHEAD + h)) * SEQ * HDK;

    // load Q tile (32x64)
    #pragma unroll
    for (int i = 0; i < 2; ++i) {
        const int e = (tid + 256*i) * 4;
        const int r = e >> 6, c = e & 63;
        const float4 qv = *(const float4*)(qd + base + (size_t)(q0 + r) * HDK + c);
        Qs[r][c] = qv.x; Qs[r][c+1] = qv.y; Qs[r][c+2] = qv.z; Qs[r][c+3] = qv.w;
    }
    if (tid < 32) { mrow[tid] = -INFINITY; lrow[tid] = 0.f; }

    float o[2][4] = {};
    const int r0 = ty * 2;
    const int c0 = tx * 4;
    const int nkt = (q0 + 31) / 64 + 1;

    for (int kt = 0; kt < nkt; ++kt) {
        const int k0 = kt * 64;
        __syncthreads();                         // prev iter done with Ks/Vs/Ss
        #pragma unroll
        for (int i = 0; i < 4; ++i) {
            const int e = (tid + 256*i) * 4;
            const int r = e >> 6, c = e & 63;
            const float4 kv = *(const float4*)(kd + base + (size_t)(k0 + r) * HDK + c);
            Ks[r][c] = kv.x; Ks[r][c+1] = kv.y; Ks[r][c+2] = kv.z; Ks[r][c+3] = kv.w;
            const float4 vv = *(const float4*)(vd + base + (size_t)(k0 + r) * HDK + c);
            *(float4*)&Vs[r][c] = vv;
        }
        __syncthreads();

        // S = (Q K^T) * 1/8, causal mask, into Ss
        float sacc[2][4] = {};
        for (int dd = 0; dd < 64; ++dd) {
            const float a0 = Qs[r0][dd], a1 = Qs[r0+1][dd];
            float bb[4];
            #pragma unroll
            for (int j = 0; j < 4; ++j) bb[j] = Ks[c0+j][dd];
            #pragma unroll
            for (int j = 0; j < 4; ++j) { sacc[0][j] += a0*bb[j]; sacc[1][j] += a1*bb[j]; }
        }
        #pragma unroll
        for (int i = 0; i < 2; ++i)
            #pragma unroll
            for (int j = 0; j < 4; ++j) {
                float s = sacc[i][j] * 0.125f;
                if (k0 + c0 + j > q0 + r0 + i) s = -INFINITY;  // causal
                Ss[r0+i][c0+j] = s;
            }
        __syncthreads();

        // online-softmax row stats: 8 threads per row
        {
            const int r = tid >> 3, l8 = tid & 7;
            const int cb = l8 * 8;
            float mx = -INFINITY;
            #pragma unroll
            for (int c = 0; c < 8; ++c) mx = fmaxf(mx, Ss[r][cb+c]);
            #pragma unroll
            for (int off = 4; off > 0; off >>= 1) mx = fmaxf(mx, __shfl_xor(mx, off));
            const float m_old = mrow[r];
            const float m_new = fmaxf(m_old, mx);
            const float alpha = expf(m_old - m_new);   // 0 on first tile
            float sum = 0.f;
            #pragma unroll
            for (int c = 0; c < 8; ++c) {
                const float p = expf(Ss[r][cb+c] - m_new);
                Ss[r][cb+c] = p;
                sum += p;
            }
            #pragma unroll
            for (int off = 4; off > 0; off >>= 1) sum += __shfl_xor(sum, off);
            if (l8 == 0) { mrow[r] = m_new; lrow[r] = lrow[r]*alpha + sum; arow[r] = alpha; }
        }
        __syncthreads();

        // O = O*alpha + P V
        const float al0 = arow[r0], al1 = arow[r0+1];
        #pragma unroll
        for (int j = 0; j < 4; ++j) { o[0][j] *= al0; o[1][j] *= al1; }
        for (int c = 0; c < 64; ++c) {
            const float p0 = Ss[r0][c], p1 = Ss[r0+1][c];
            float vv[4];
            #pragma unroll
            for (int j = 0; j < 4; ++j) vv[j] = Vs[c][c0+j];
            #pragma unroll
            for (int j = 0; j < 4; ++j) { o[0][j] += p0*vv[j]; o[1][j] += p1*vv[j]; }
        }
    }

    // normalize + store as (B,T,H,DK)
    #pragma unroll
    for (int i = 0; i < 2; ++i) {
        const float inv = 1.f / lrow[r0+i];
        float4 vout = { o[i][0]*inv, o[i][1]*inv, o[i][2]*inv, o[i][3]*inv };
        const size_t off = ((size_t)(b*SEQ + (q0 + r0 + i)) * NHEAD + h) * HDK + c0;
        *(float4*)(od + off) = vout;
    }
}

// ---------------------------------------------------------------------------
// Kernel C: out = attn @ W_out + b_out. grid (DMODEL/64, MROWS/64), block 256.
// ---------------------------------------------------------------------------
__global__ __launch_bounds__(256) void out_gemm_kernel(
    const float* __restrict__ A, const float* __restrict__ W,
    const float* __restrict__ bias, float* __restrict__ out)
{
    __shared__ float As[16][64];
    __shared__ float Bs[16][64];
    const int tid = threadIdx.x;
    const int tx = tid & 15, ty = tid >> 4;
    const int n0 = blockIdx.x * 64;
    const int m0 = blockIdx.y * 64;
    float acc[4][4] = {};

    for (int k0 = 0; k0 < DMODEL; k0 += 16) {
        const int e = tid * 4;
        const int arow = e >> 4, akk = e & 15;
        const float4 av = *(const float4*)(A + (size_t)(m0 + arow) * DMODEL + k0 + akk);
        const int bkk = e >> 6, bcol = e & 63;
        const float4 bv = *(const float4*)(W + (size_t)(k0 + bkk) * DMODEL + n0 + bcol);
        __syncthreads();
        As[akk+0][arow] = av.x; As[akk+1][arow] = av.y;
        As[akk+2][arow] = av.z; As[akk+3][arow] = av.w;
        *(float4*)&Bs[bkk][bcol] = bv;
        __syncthreads();
        #pragma unroll
        for (int kk = 0; kk < 16; ++kk) {
            float a[4], bb[4];
            #pragma unroll
            for (int i = 0; i < 4; ++i) a[i]  = As[kk][ty*4+i];
            #pragma unroll
            for (int j = 0; j < 4; ++j) bb[j] = Bs[kk][tx*4+j];
            #pragma unroll
            for (int i = 0; i < 4; ++i)
                #pragma unroll
                for (int j = 0; j < 4; ++j)
                    acc[i][j] += a[i]*bb[j];
        }
    }

    const int n = n0 + tx*4;
    const float b0 = bias[n+0], b1 = bias[n+1], b2 = bias[n+2], b3 = bias[n+3];
    #pragma unroll
    for (int i = 0; i < 4; ++i) {
        const int m = m0 + ty*4 + i;
        float4 vout = { acc[i][0]+b0, acc[i][1]+b1, acc[i][2]+b2, acc[i][3]+b3 };
        *(float4*)(out + (size_t)m * DMODEL + n) = vout;
    }
}

// ---------------------------------------------------------------------------
extern "C" void kernel_launch(void* const* d_in, const int* in_sizes, int n_in,
                              void* d_out, int out_size, void* d_ws, size_t ws_size,
                              hipStream_t stream) {
    const float* x    = (const float*)d_in[0];
    const float* Wqkv = (const float*)d_in[1];
    const float* bqkv = (const float*)d_in[2];
    const float* Wout = (const float*)d_in[3];
    const float* bout = (const float*)d_in[4];
    float* out = (float*)d_out;

    float* ws = (float*)d_ws;
    const size_t HEADS_ELEMS = (size_t)BATCH * NHEAD * SEQ * HDK; // 4,194,304
    float* q_ws    = ws;
    float* k_ws    = ws + HEADS_ELEMS;
    float* v_ws    = ws + 2*HEADS_ELEMS;
    float* attn_ws = ws + 3*HEADS_ELEMS;

    dim3 gA(NQKV/64, MROWS/64);
    qkv_rope_kernel<<<gA, 256, 0, stream>>>(x, Wqkv, bqkv, q_ws, k_ws, v_ws);

    dim3 gB(SEQ/32, NHEAD, BATCH);
    attn_kernel<<<gB, 256, 0, stream>>>(q_ws, k_ws, v_ws, attn_ws);

    dim3 gC(DMODEL/64, MROWS/64);
    out_gemm_kernel<<<gC, 256, 0, stream>>>(attn_ws, Wout, bout, out);
}

// Round 2
// 356.785 us; speedup vs baseline: 3.6936x; 3.6936x over previous
//
#include <hip/hip_runtime.h>
#include <math.h>

#define DMODEL 1024
#define NHEAD  16
#define HDK    64
#define BATCH  2
#define SEQ    2048
#define MROWS  (BATCH*SEQ)   // 4096
#define NQKV   (3*DMODEL)    // 3072
#define LOG2_10000 13.287712379549449f

typedef __attribute__((ext_vector_type(8))) short bf16x8;
typedef __attribute__((ext_vector_type(4))) float f32x4;

__device__ __forceinline__ short f2bf(float f) {
    union { float f; unsigned u; } v; v.f = f;
    unsigned r = v.u + 0x7fffu + ((v.u >> 16) & 1u);
    return (short)(r >> 16);
}

// ---------------------------------------------------------------------------
// fp32 -> bf16 elementwise (n must be multiple of 8*256)
// ---------------------------------------------------------------------------
__global__ __launch_bounds__(256) void convert_kernel(
    const float* __restrict__ in, short* __restrict__ out, int n)
{
    int i = (blockIdx.x * 256 + threadIdx.x) * 8;
    if (i >= n) return;
    float4 a = *(const float4*)(in + i);
    float4 b = *(const float4*)(in + i + 4);
    bf16x8 o;
    o[0] = f2bf(a.x); o[1] = f2bf(a.y); o[2] = f2bf(a.z); o[3] = f2bf(a.w);
    o[4] = f2bf(b.x); o[5] = f2bf(b.y); o[6] = f2bf(b.z); o[7] = f2bf(b.w);
    *(bf16x8*)(out + i) = o;
}

// ---------------------------------------------------------------------------
// fp32 (K,N) row-major -> bf16 (N,K) row-major. block (32,8), grid (N/32,K/32)
// ---------------------------------------------------------------------------
__global__ __launch_bounds__(256) void transpose_convert_kernel(
    const float* __restrict__ in, short* __restrict__ out, int K, int N)
{
    __shared__ short tile[32][33];
    const int tx = threadIdx.x, ty = threadIdx.y;
    const int n0 = blockIdx.x * 32, k0 = blockIdx.y * 32;
    #pragma unroll
    for (int i = 0; i < 32; i += 8)
        tile[ty + i][tx] = f2bf(in[(size_t)(k0 + ty + i) * N + n0 + tx]);
    __syncthreads();
    #pragma unroll
    for (int i = 0; i < 32; i += 8)
        out[(size_t)(n0 + ty + i) * K + k0 + tx] = tile[tx][ty + i];
}

// ---------------------------------------------------------------------------
// QKV GEMM (MFMA bf16): C = x @ W_qkv + b, fused RoPE, scatter to (B,H,T,DK)
// A: xb (M,K) bf16.  B: Wt (N,K) bf16 (pre-transposed).  grid(NQKV/128, M/128)
// 256 thr = 4 waves, wave -> 64x64 quadrant (4x4 tiles of 16x16), BK=32.
// ---------------------------------------------------------------------------
__global__ __launch_bounds__(256) void qkv_gemm_kernel(
    const short* __restrict__ xb, const short* __restrict__ Wt,
    const float* __restrict__ bias,
    short* __restrict__ qd, short* __restrict__ kd, short* __restrict__ vd)
{
    __shared__ __align__(16) short As[128][40];
    __shared__ __align__(16) short Bs[128][40];
    const int tid = threadIdx.x;
    const int lane = tid & 63, wave = tid >> 6;
    const int wm = wave & 1, wn = wave >> 1;
    const int l15 = lane & 15, quad = lane >> 4;
    const int n0 = blockIdx.x * 128, m0 = blockIdx.y * 128;
    const int srow = tid >> 1, skh = (tid & 1) * 16;

    f32x4 zero = {0.f, 0.f, 0.f, 0.f};
    f32x4 acc[4][4];
    #pragma unroll
    for (int i = 0; i < 4; ++i)
        #pragma unroll
        for (int j = 0; j < 4; ++j) acc[i][j] = zero;

    for (int k0 = 0; k0 < DMODEL; k0 += 32) {
        const short* ap = xb + (size_t)(m0 + srow) * DMODEL + k0 + skh;
        const short* bp = Wt + (size_t)(n0 + srow) * DMODEL + k0 + skh;
        bf16x8 a0 = *(const bf16x8*)ap, a1 = *(const bf16x8*)(ap + 8);
        bf16x8 b0 = *(const bf16x8*)bp, b1 = *(const bf16x8*)(bp + 8);
        __syncthreads();
        *(bf16x8*)&As[srow][skh] = a0; *(bf16x8*)&As[srow][skh + 8] = a1;
        *(bf16x8*)&Bs[srow][skh] = b0; *(bf16x8*)&Bs[srow][skh + 8] = b1;
        __syncthreads();
        bf16x8 af[4], bfr[4];
        #pragma unroll
        for (int i = 0; i < 4; ++i)
            af[i] = *(const bf16x8*)&As[wm * 64 + i * 16 + l15][quad * 8];
        #pragma unroll
        for (int j = 0; j < 4; ++j)
            bfr[j] = *(const bf16x8*)&Bs[wn * 64 + j * 16 + l15][quad * 8];
        #pragma unroll
        for (int i = 0; i < 4; ++i)
            #pragma unroll
            for (int j = 0; j < 4; ++j)
                acc[i][j] = __builtin_amdgcn_mfma_f32_16x16x32_bf16(af[i], bfr[j], acc[i][j], 0, 0, 0);
    }

    // epilogue: bias + RoPE (q,k) + scatter bf16 to (B,H,T,DK)
    const int which = n0 >> 10;   // block fully within q/k/v (n0 mult of 128)
    short* dst = (which == 0) ? qd : (which == 1) ? kd : vd;
    float biasv[4], invf[4];
    int hh[4], dd[4];
    #pragma unroll
    for (int j = 0; j < 4; ++j) {
        const int n = n0 + wn * 64 + j * 16 + l15;
        biasv[j] = bias[n];
        hh[j] = (n & 1023) >> 6;
        dd[j] = n & 63;
        invf[j] = exp2f(-((float)(dd[j] & ~1) / 64.f) * LOG2_10000);
    }
    #pragma unroll
    for (int i = 0; i < 4; ++i) {
        #pragma unroll
        for (int r = 0; r < 4; ++r) {
            const int m = m0 + wm * 64 + i * 16 + quad * 4 + r;
            const int b = m >> 11, t = m & (SEQ - 1);
            #pragma unroll
            for (int j = 0; j < 4; ++j) {
                float val = acc[i][j][r] + biasv[j];
                if (which < 2) {
                    float s, c;
                    sincosf((float)t * invf[j], &s, &c);
                    const float partner = __shfl_xor(val, 1);
                    val = (lane & 1) ? (partner * s + val * c) : (val * c - partner * s);
                }
                dst[((size_t)(b * NHEAD + hh[j]) * SEQ + t) * HDK + dd[j]] = f2bf(val);
            }
        }
    }
}

// ---------------------------------------------------------------------------
// Flash attention (MFMA bf16): grid (SEQ/64, NHEAD, BATCH), 256 thr = 4 waves.
// Block = 64 Q rows; wave w owns rows q0+16w..+15. K/V tiles of 64 in LDS.
// Output bf16 as (B,T,H,DK).
// ---------------------------------------------------------------------------
__global__ __launch_bounds__(256) void attn_mfma_kernel(
    const short* __restrict__ qd, const short* __restrict__ kd,
    const short* __restrict__ vd, short* __restrict__ od)
{
    __shared__ __align__(16) short Ks[64][72];
    __shared__ __align__(16) short Vt[64][72];     // V transposed: Vt[d][s]
    __shared__ __align__(16) short Ps[4][16][72];  // per-wave P tile
    const int tid = threadIdx.x, lane = tid & 63, w = tid >> 6;
    const int l15 = lane & 15, quad = lane >> 4;
    const int q0 = (int)(gridDim.x - 1 - blockIdx.x) * 64;  // heavy blocks first
    const int h = blockIdx.y, b = blockIdx.z;
    const size_t base = ((size_t)(b * NHEAD + h)) * SEQ * HDK;

    f32x4 zero = {0.f, 0.f, 0.f, 0.f};
    bf16x8 qf[2];
    {
        const short* qrow = qd + base + (size_t)(q0 + w * 16 + l15) * HDK;
        qf[0] = *(const bf16x8*)(qrow + quad * 8);
        qf[1] = *(const bf16x8*)(qrow + 32 + quad * 8);
    }
    float m_i[4], l_i[4];
    f32x4 o[4];
    #pragma unroll
    for (int r = 0; r < 4; ++r) { m_i[r] = -INFINITY; l_i[r] = 0.f; }
    #pragma unroll
    for (int j = 0; j < 4; ++j) o[j] = zero;

    const int srow = tid >> 2, sdh = (tid & 3) * 16;
    const int nkt = q0 / 64 + 1;

    for (int kt = 0; kt < nkt; ++kt) {
        const int s0 = kt * 64;
        const short* kp = kd + base + (size_t)(s0 + srow) * HDK + sdh;
        const short* vp = vd + base + (size_t)(s0 + srow) * HDK + sdh;
        bf16x8 k0v = *(const bf16x8*)kp, k1v = *(const bf16x8*)(kp + 8);
        bf16x8 v0v = *(const bf16x8*)vp, v1v = *(const bf16x8*)(vp + 8);
        __syncthreads();                  // prev iter done with Ks/Vt
        *(bf16x8*)&Ks[srow][sdh] = k0v; *(bf16x8*)&Ks[srow][sdh + 8] = k1v;
        #pragma unroll
        for (int jj = 0; jj < 8; ++jj) {
            Vt[sdh + jj][srow]     = v0v[jj];
            Vt[sdh + 8 + jj][srow] = v1v[jj];
        }
        __syncthreads();

        // S = Q K^T (4 n-tiles x 2 k-steps)
        f32x4 sacc[4];
        #pragma unroll
        for (int j = 0; j < 4; ++j) {
            bf16x8 kf0 = *(const bf16x8*)&Ks[j * 16 + l15][quad * 8];
            bf16x8 kf1 = *(const bf16x8*)&Ks[j * 16 + l15][32 + quad * 8];
            sacc[j] = __builtin_amdgcn_mfma_f32_16x16x32_bf16(qf[0], kf0, zero, 0, 0, 0);
            sacc[j] = __builtin_amdgcn_mfma_f32_16x16x32_bf16(qf[1], kf1, sacc[j], 0, 0, 0);
        }
        // scale + causal mask + row max
        float mx[4] = {-INFINITY, -INFINITY, -INFINITY, -INFINITY};
        #pragma unroll
        for (int j = 0; j < 4; ++j) {
            const int scol = s0 + j * 16 + l15;
            #pragma unroll
            for (int r = 0; r < 4; ++r) {
                const int trow = q0 + w * 16 + quad * 4 + r;
                float sv = sacc[j][r] * 0.125f;
                sv = (scol > trow) ? -INFINITY : sv;
                sacc[j][r] = sv;
                mx[r] = fmaxf(mx[r], sv);
            }
        }
        #pragma unroll
        for (int r = 0; r < 4; ++r) {
            #pragma unroll
            for (int off = 1; off < 16; off <<= 1)
                mx[r] = fmaxf(mx[r], __shfl_xor(mx[r], off));
        }
        float alpha[4];
        #pragma unroll
        for (int r = 0; r < 4; ++r) {
            const float mn = fmaxf(m_i[r], mx[r]);
            alpha[r] = expf(m_i[r] - mn);
            m_i[r] = mn;
        }
        // p = exp(s - m), write to LDS (bf16), row sums
        float rs[4] = {0.f, 0.f, 0.f, 0.f};
        #pragma unroll
        for (int j = 0; j < 4; ++j)
            #pragma unroll
            for (int r = 0; r < 4; ++r) {
                const float p = expf(sacc[j][r] - m_i[r]);
                rs[r] += p;
                Ps[w][quad * 4 + r][j * 16 + l15] = f2bf(p);
            }
        #pragma unroll
        for (int r = 0; r < 4; ++r) {
            float sr = rs[r];
            #pragma unroll
            for (int off = 1; off < 16; off <<= 1) sr += __shfl_xor(sr, off);
            l_i[r] = l_i[r] * alpha[r] + sr;
        }
        // O = O*alpha + P V   (P per-wave: same-wave LDS RAW, no barrier needed)
        #pragma unroll
        for (int j = 0; j < 4; ++j)
            #pragma unroll
            for (int r = 0; r < 4; ++r) o[j][r] *= alpha[r];
        bf16x8 pf0 = *(const bf16x8*)&Ps[w][l15][quad * 8];
        bf16x8 pf1 = *(const bf16x8*)&Ps[w][l15][32 + quad * 8];
        #pragma unroll
        for (int j = 0; j < 4; ++j) {
            bf16x8 vf0 = *(const bf16x8*)&Vt[j * 16 + l15][quad * 8];
            bf16x8 vf1 = *(const bf16x8*)&Vt[j * 16 + l15][32 + quad * 8];
            o[j] = __builtin_amdgcn_mfma_f32_16x16x32_bf16(pf0, vf0, o[j], 0, 0, 0);
            o[j] = __builtin_amdgcn_mfma_f32_16x16x32_bf16(pf1, vf1, o[j], 0, 0, 0);
        }
    }

    // normalize + store bf16 as (B,T,H,DK)
    #pragma unroll
    for (int r = 0; r < 4; ++r) {
        const float inv = 1.f / l_i[r];
        const int t = q0 + w * 16 + quad * 4 + r;
        #pragma unroll
        for (int j = 0; j < 4; ++j)
            od[((size_t)(b * SEQ + t) * NHEAD + h) * HDK + j * 16 + l15] =
                f2bf(o[j][r] * inv);
    }
}

// ---------------------------------------------------------------------------
// Output GEMM (MFMA bf16): out = attn @ W_out + b_out (fp32 out)
// ---------------------------------------------------------------------------
__global__ __launch_bounds__(256) void out_gemm_kernel(
    const short* __restrict__ Ab, const short* __restrict__ Wt,
    const float* __restrict__ bias, float* __restrict__ out)
{
    __shared__ __align__(16) short As[128][40];
    __shared__ __align__(16) short Bs[128][40];
    const int tid = threadIdx.x;
    const int lane = tid & 63, wave = tid >> 6;
    const int wm = wave & 1, wn = wave >> 1;
    const int l15 = lane & 15, quad = lane >> 4;
    const int n0 = blockIdx.x * 128, m0 = blockIdx.y * 128;
    const int srow = tid >> 1, skh = (tid & 1) * 16;

    f32x4 zero = {0.f, 0.f, 0.f, 0.f};
    f32x4 acc[4][4];
    #pragma unroll
    for (int i = 0; i < 4; ++i)
        #pragma unroll
        for (int j = 0; j < 4; ++j) acc[i][j] = zero;

    for (int k0 = 0; k0 < DMODEL; k0 += 32) {
        const short* ap = Ab + (size_t)(m0 + srow) * DMODEL + k0 + skh;
        const short* bp = Wt + (size_t)(n0 + srow) * DMODEL + k0 + skh;
        bf16x8 a0 = *(const bf16x8*)ap, a1 = *(const bf16x8*)(ap + 8);
        bf16x8 b0 = *(const bf16x8*)bp, b1 = *(const bf16x8*)(bp + 8);
        __syncthreads();
        *(bf16x8*)&As[srow][skh] = a0; *(bf16x8*)&As[srow][skh + 8] = a1;
        *(bf16x8*)&Bs[srow][skh] = b0; *(bf16x8*)&Bs[srow][skh + 8] = b1;
        __syncthreads();
        bf16x8 af[4], bfr[4];
        #pragma unroll
        for (int i = 0; i < 4; ++i)
            af[i] = *(const bf16x8*)&As[wm * 64 + i * 16 + l15][quad * 8];
        #pragma unroll
        for (int j = 0; j < 4; ++j)
            bfr[j] = *(const bf16x8*)&Bs[wn * 64 + j * 16 + l15][quad * 8];
        #pragma unroll
        for (int i = 0; i < 4; ++i)
            #pragma unroll
            for (int j = 0; j < 4; ++j)
                acc[i][j] = __builtin_amdgcn_mfma_f32_16x16x32_bf16(af[i], bfr[j], acc[i][j], 0, 0, 0);
    }

    #pragma unroll
    for (int j = 0; j < 4; ++j) {
        const int n = n0 + wn * 64 + j * 16 + l15;
        const float bv = bias[n];
        #pragma unroll
        for (int i = 0; i < 4; ++i)
            #pragma unroll
            for (int r = 0; r < 4; ++r) {
                const int m = m0 + wm * 64 + i * 16 + quad * 4 + r;
                out[(size_t)m * DMODEL + n] = acc[i][j][r] + bv;
            }
    }
}

// ---------------------------------------------------------------------------
extern "C" void kernel_launch(void* const* d_in, const int* in_sizes, int n_in,
                              void* d_out, int out_size, void* d_ws, size_t ws_size,
                              hipStream_t stream) {
    const float* x    = (const float*)d_in[0];
    const float* Wqkv = (const float*)d_in[1];
    const float* bqkv = (const float*)d_in[2];
    const float* Wout = (const float*)d_in[3];
    const float* bout = (const float*)d_in[4];
    float* out = (float*)d_out;

    short* ws = (short*)d_ws;
    short* xb     = ws;                                // 4M elems
    short* wqkv_t = xb + (size_t)4 * 1024 * 1024;      // 3M
    short* wout_t = wqkv_t + (size_t)3 * 1024 * 1024;  // 1M
    short* qd     = wout_t + (size_t)1024 * 1024;      // 4M
    short* kd     = qd + (size_t)4 * 1024 * 1024;      // 4M
    short* vd     = kd + (size_t)4 * 1024 * 1024;      // 4M
    short* attn   = vd + (size_t)4 * 1024 * 1024;      // 4M  (total 48 MB)

    convert_kernel<<<(MROWS * DMODEL) / (256 * 8), 256, 0, stream>>>(
        x, xb, MROWS * DMODEL);
    transpose_convert_kernel<<<dim3(NQKV / 32, DMODEL / 32), dim3(32, 8), 0, stream>>>(
        Wqkv, wqkv_t, DMODEL, NQKV);
    transpose_convert_kernel<<<dim3(DMODEL / 32, DMODEL / 32), dim3(32, 8), 0, stream>>>(
        Wout, wout_t, DMODEL, DMODEL);

    qkv_gemm_kernel<<<dim3(NQKV / 128, MROWS / 128), 256, 0, stream>>>(
        xb, wqkv_t, bqkv, qd, kd, vd);

    attn_mfma_kernel<<<dim3(SEQ / 64, NHEAD, BATCH), 256, 0, stream>>>(
        qd, kd, vd, attn);

    out_gemm_kernel<<<dim3(DMODEL / 128, MROWS / 128), 256, 0, stream>>>(
        attn, wout_t, bout, out);
}

// Round 3
// 229.467 us; speedup vs baseline: 5.7430x; 1.5548x over previous
//
#include <hip/hip_runtime.h>
#include <math.h>

#define DMODEL 1024
#define NHEAD  16
#define HDK    64
#define BATCH  2
#define SEQ    2048
#define MROWS  (BATCH*SEQ)   // 4096
#define NQKV   (3*DMODEL)    // 3072
#define LOG2_10000 13.287712379549449f
#define INV2PI 0.15915494309189535f
#define SCALE_LOG2E 0.1803368801111137f   // 0.125 * log2(e)

typedef __attribute__((ext_vector_type(8))) short bf16x8;
typedef __attribute__((ext_vector_type(4))) float f32x4;

__device__ __forceinline__ short f2bf(float f) {
    union { float f; unsigned u; } v; v.f = f;
    unsigned r = v.u + 0x7fffu + ((v.u >> 16) & 1u);
    return (short)(r >> 16);
}

__device__ __forceinline__ float fast_exp2(float x) {
#if __has_builtin(__builtin_amdgcn_exp2f)
    return __builtin_amdgcn_exp2f(x);
#else
    return exp2f(x);
#endif
}

// ---------------------------------------------------------------------------
// fp32 -> bf16 elementwise
// ---------------------------------------------------------------------------
__global__ __launch_bounds__(256) void convert_kernel(
    const float* __restrict__ in, short* __restrict__ out, int n)
{
    int i = (blockIdx.x * 256 + threadIdx.x) * 8;
    if (i >= n) return;
    float4 a = *(const float4*)(in + i);
    float4 b = *(const float4*)(in + i + 4);
    bf16x8 o;
    o[0] = f2bf(a.x); o[1] = f2bf(a.y); o[2] = f2bf(a.z); o[3] = f2bf(a.w);
    o[4] = f2bf(b.x); o[5] = f2bf(b.y); o[6] = f2bf(b.z); o[7] = f2bf(b.w);
    *(bf16x8*)(out + i) = o;
}

// ---------------------------------------------------------------------------
// fp32 (K,N) row-major -> bf16 (N,K) row-major. block (32,8), grid (N/32,K/32)
// ---------------------------------------------------------------------------
__global__ __launch_bounds__(256) void transpose_convert_kernel(
    const float* __restrict__ in, short* __restrict__ out, int K, int N)
{
    __shared__ short tile[32][33];
    const int tx = threadIdx.x, ty = threadIdx.y;
    const int n0 = blockIdx.x * 32, k0 = blockIdx.y * 32;
    #pragma unroll
    for (int i = 0; i < 32; i += 8)
        tile[ty + i][tx] = f2bf(in[(size_t)(k0 + ty + i) * N + n0 + tx]);
    __syncthreads();
    #pragma unroll
    for (int i = 0; i < 32; i += 8)
        out[(size_t)(n0 + ty + i) * K + k0 + tx] = tile[tx][ty + i];
}

// ---------------------------------------------------------------------------
// bf16 V (B,H,S,D) -> Vt (B,H,D,S). grid (SEQ/64, B*H), 256 thr.
// ---------------------------------------------------------------------------
__global__ __launch_bounds__(256) void transpose_v_kernel(
    const short* __restrict__ v, short* __restrict__ vt)
{
    __shared__ short tile[64][72];
    const int tid = threadIdx.x;
    const int s0 = blockIdx.x * 64;
    const size_t base = (size_t)blockIdx.y * SEQ * HDK;
    const int r = tid >> 2, c = (tid & 3) * 16;
    bf16x8 a0 = *(const bf16x8*)(v + base + (size_t)(s0 + r) * HDK + c);
    bf16x8 a1 = *(const bf16x8*)(v + base + (size_t)(s0 + r) * HDK + c + 8);
    *(bf16x8*)&tile[r][c] = a0;
    *(bf16x8*)&tile[r][c + 8] = a1;
    __syncthreads();
    const int d = tid >> 2, sc = (tid & 3) * 16;
    bf16x8 o0, o1;
    #pragma unroll
    for (int i = 0; i < 8; ++i) { o0[i] = tile[sc + i][d]; o1[i] = tile[sc + 8 + i][d]; }
    *(bf16x8*)(vt + base + (size_t)d * SEQ + s0 + sc) = o0;
    *(bf16x8*)(vt + base + (size_t)d * SEQ + s0 + sc + 8) = o1;
}

// ---------------------------------------------------------------------------
// QKV GEMM (MFMA bf16) + bias + RoPE + scatter to (B,H,T,DK)
// ---------------------------------------------------------------------------
__global__ __launch_bounds__(256) void qkv_gemm_kernel(
    const short* __restrict__ xb, const short* __restrict__ Wt,
    const float* __restrict__ bias,
    short* __restrict__ qd, short* __restrict__ kd, short* __restrict__ vd)
{
    __shared__ __align__(16) short As[128][40];
    __shared__ __align__(16) short Bs[128][40];
    const int tid = threadIdx.x;
    const int lane = tid & 63, wave = tid >> 6;
    const int wm = wave & 1, wn = wave >> 1;
    const int l15 = lane & 15, quad = lane >> 4;
    const int n0 = blockIdx.x * 128, m0 = blockIdx.y * 128;
    const int srow = tid >> 1, skh = (tid & 1) * 16;

    f32x4 zero = {0.f, 0.f, 0.f, 0.f};
    f32x4 acc[4][4];
    #pragma unroll
    for (int i = 0; i < 4; ++i)
        #pragma unroll
        for (int j = 0; j < 4; ++j) acc[i][j] = zero;

    for (int k0 = 0; k0 < DMODEL; k0 += 32) {
        const short* ap = xb + (size_t)(m0 + srow) * DMODEL + k0 + skh;
        const short* bp = Wt + (size_t)(n0 + srow) * DMODEL + k0 + skh;
        bf16x8 a0 = *(const bf16x8*)ap, a1 = *(const bf16x8*)(ap + 8);
        bf16x8 b0 = *(const bf16x8*)bp, b1 = *(const bf16x8*)(bp + 8);
        __syncthreads();
        *(bf16x8*)&As[srow][skh] = a0; *(bf16x8*)&As[srow][skh + 8] = a1;
        *(bf16x8*)&Bs[srow][skh] = b0; *(bf16x8*)&Bs[srow][skh + 8] = b1;
        __syncthreads();
        bf16x8 af[4], bfr[4];
        #pragma unroll
        for (int i = 0; i < 4; ++i)
            af[i] = *(const bf16x8*)&As[wm * 64 + i * 16 + l15][quad * 8];
        #pragma unroll
        for (int j = 0; j < 4; ++j)
            bfr[j] = *(const bf16x8*)&Bs[wn * 64 + j * 16 + l15][quad * 8];
        #pragma unroll
        for (int i = 0; i < 4; ++i)
            #pragma unroll
            for (int j = 0; j < 4; ++j)
                acc[i][j] = __builtin_amdgcn_mfma_f32_16x16x32_bf16(af[i], bfr[j], acc[i][j], 0, 0, 0);
    }

    const int which = n0 >> 10;
    short* dst = (which == 0) ? qd : (which == 1) ? kd : vd;
    float biasv[4], invf[4];
    int hh[4], dd[4];
    #pragma unroll
    for (int j = 0; j < 4; ++j) {
        const int n = n0 + wn * 64 + j * 16 + l15;
        biasv[j] = bias[n];
        hh[j] = (n & 1023) >> 6;
        dd[j] = n & 63;
        invf[j] = INV2PI * exp2f(-((float)(dd[j] & ~1) / 64.f) * LOG2_10000);
    }
    #pragma unroll
    for (int i = 0; i < 4; ++i) {
        #pragma unroll
        for (int r = 0; r < 4; ++r) {
            const int m = m0 + wm * 64 + i * 16 + quad * 4 + r;
            const int b = m >> 11, t = m & (SEQ - 1);
            #pragma unroll
            for (int j = 0; j < 4; ++j) {
                float val = acc[i][j][r] + biasv[j];
                if (which < 2) {
                    const float rev = (float)t * invf[j];
                    const float fr = rev - floorf(rev);      // revolutions in [0,1)
                    const float s = __builtin_amdgcn_sinf(fr);
                    const float c = __builtin_amdgcn_cosf(fr);
                    const float partner = __shfl_xor(val, 1);
                    val = (lane & 1) ? (partner * s + val * c) : (val * c - partner * s);
                }
                dst[((size_t)(b * NHEAD + hh[j]) * SEQ + t) * HDK + dd[j]] = f2bf(val);
            }
        }
    }
}

// ---------------------------------------------------------------------------
// Flash attention (MFMA bf16), load-balanced: block handles Q-tiles i and 31-i.
// grid (16, NHEAD, BATCH), 256 thr = 4 waves; wave w owns 16 Q-rows.
// K in (B,H,S,D); V pre-transposed (B,H,D,S). Output bf16 (B,T,H,DK).
// ---------------------------------------------------------------------------
__global__ __launch_bounds__(256) void attn_mfma_kernel(
    const short* __restrict__ qd, const short* __restrict__ kd,
    const short* __restrict__ vt, short* __restrict__ od)
{
    __shared__ __align__(16) short Ks[64][72];
    __shared__ __align__(16) short Vs[64][72];     // Vs[d][s]
    __shared__ __align__(16) short Ps[4][16][72];  // per-wave P tile
    const int tid = threadIdx.x, lane = tid & 63, w = tid >> 6;
    const int l15 = lane & 15, quad = lane >> 4;
    const int h = blockIdx.y, b = blockIdx.z;
    const size_t base = ((size_t)(b * NHEAD + h)) * SEQ * HDK;
    const int srow = tid >> 2, sdh = (tid & 3) * 16;
    f32x4 zero = {0.f, 0.f, 0.f, 0.f};

    const int qtile[2] = { (int)blockIdx.x, 31 - (int)blockIdx.x };

    #pragma unroll 1
    for (int qi = 0; qi < 2; ++qi) {
        const int q0 = qtile[qi] * 64;
        bf16x8 qf[2];
        {
            const short* qrow = qd + base + (size_t)(q0 + w * 16 + l15) * HDK;
            qf[0] = *(const bf16x8*)(qrow + quad * 8);
            qf[1] = *(const bf16x8*)(qrow + 32 + quad * 8);
        }
        float m_i[4], l_i[4];
        f32x4 o[4];
        #pragma unroll
        for (int r = 0; r < 4; ++r) { m_i[r] = -INFINITY; l_i[r] = 0.f; }
        #pragma unroll
        for (int j = 0; j < 4; ++j) o[j] = zero;

        const int nkt = q0 / 64 + 1;
        for (int kt = 0; kt < nkt; ++kt) {
            const int s0 = kt * 64;
            const short* kp = kd + base + (size_t)(s0 + srow) * HDK + sdh;
            const short* vp = vt + base + (size_t)srow * SEQ + s0 + sdh;
            bf16x8 k0v = *(const bf16x8*)kp, k1v = *(const bf16x8*)(kp + 8);
            bf16x8 v0v = *(const bf16x8*)vp, v1v = *(const bf16x8*)(vp + 8);
            __syncthreads();                  // prev iter done with Ks/Vs
            *(bf16x8*)&Ks[srow][sdh] = k0v; *(bf16x8*)&Ks[srow][sdh + 8] = k1v;
            *(bf16x8*)&Vs[srow][sdh] = v0v; *(bf16x8*)&Vs[srow][sdh + 8] = v1v;
            __syncthreads();

            // S = Q K^T, in exp2 domain (scaled by 0.125*log2e)
            f32x4 sacc[4];
            #pragma unroll
            for (int j = 0; j < 4; ++j) {
                bf16x8 kf0 = *(const bf16x8*)&Ks[j * 16 + l15][quad * 8];
                bf16x8 kf1 = *(const bf16x8*)&Ks[j * 16 + l15][32 + quad * 8];
                sacc[j] = __builtin_amdgcn_mfma_f32_16x16x32_bf16(qf[0], kf0, zero, 0, 0, 0);
                sacc[j] = __builtin_amdgcn_mfma_f32_16x16x32_bf16(qf[1], kf1, sacc[j], 0, 0, 0);
            }
            float mx[4] = {-INFINITY, -INFINITY, -INFINITY, -INFINITY};
            if (kt == nkt - 1) {              // diagonal tile: mask needed
                #pragma unroll
                for (int j = 0; j < 4; ++j) {
                    const int scol = s0 + j * 16 + l15;
                    #pragma unroll
                    for (int r = 0; r < 4; ++r) {
                        const int trow = q0 + w * 16 + quad * 4 + r;
                        float sv = sacc[j][r] * SCALE_LOG2E;
                        sv = (scol > trow) ? -INFINITY : sv;
                        sacc[j][r] = sv;
                        mx[r] = fmaxf(mx[r], sv);
                    }
                }
            } else {
                #pragma unroll
                for (int j = 0; j < 4; ++j)
                    #pragma unroll
                    for (int r = 0; r < 4; ++r) {
                        const float sv = sacc[j][r] * SCALE_LOG2E;
                        sacc[j][r] = sv;
                        mx[r] = fmaxf(mx[r], sv);
                    }
            }
            #pragma unroll
            for (int r = 0; r < 4; ++r) {
                #pragma unroll
                for (int off = 1; off < 16; off <<= 1)
                    mx[r] = fmaxf(mx[r], __shfl_xor(mx[r], off));
            }
            float alpha[4];
            #pragma unroll
            for (int r = 0; r < 4; ++r) {
                const float mn = fmaxf(m_i[r], mx[r]);
                alpha[r] = fast_exp2(m_i[r] - mn);
                m_i[r] = mn;
            }
            float rs[4] = {0.f, 0.f, 0.f, 0.f};
            #pragma unroll
            for (int j = 0; j < 4; ++j)
                #pragma unroll
                for (int r = 0; r < 4; ++r) {
                    const float p = fast_exp2(sacc[j][r] - m_i[r]);
                    rs[r] += p;
                    Ps[w][quad * 4 + r][j * 16 + l15] = f2bf(p);
                }
            #pragma unroll
            for (int r = 0; r < 4; ++r) {
                float sr = rs[r];
                #pragma unroll
                for (int off = 1; off < 16; off <<= 1) sr += __shfl_xor(sr, off);
                l_i[r] = l_i[r] * alpha[r] + sr;
            }
            #pragma unroll
            for (int j = 0; j < 4; ++j)
                #pragma unroll
                for (int r = 0; r < 4; ++r) o[j][r] *= alpha[r];
            bf16x8 pf0 = *(const bf16x8*)&Ps[w][l15][quad * 8];
            bf16x8 pf1 = *(const bf16x8*)&Ps[w][l15][32 + quad * 8];
            #pragma unroll
            for (int j = 0; j < 4; ++j) {
                bf16x8 vf0 = *(const bf16x8*)&Vs[j * 16 + l15][quad * 8];
                bf16x8 vf1 = *(const bf16x8*)&Vs[j * 16 + l15][32 + quad * 8];
                o[j] = __builtin_amdgcn_mfma_f32_16x16x32_bf16(pf0, vf0, o[j], 0, 0, 0);
                o[j] = __builtin_amdgcn_mfma_f32_16x16x32_bf16(pf1, vf1, o[j], 0, 0, 0);
            }
        }

        #pragma unroll
        for (int r = 0; r < 4; ++r) {
            const float inv = 1.f / l_i[r];
            const int t = q0 + w * 16 + quad * 4 + r;
            #pragma unroll
            for (int j = 0; j < 4; ++j)
                od[((size_t)(b * SEQ + t) * NHEAD + h) * HDK + j * 16 + l15] =
                    f2bf(o[j][r] * inv);
        }
    }
}

// ---------------------------------------------------------------------------
// Output GEMM (MFMA bf16): out = attn @ W_out + b_out (fp32 out)
// ---------------------------------------------------------------------------
__global__ __launch_bounds__(256) void out_gemm_kernel(
    const short* __restrict__ Ab, const short* __restrict__ Wt,
    const float* __restrict__ bias, float* __restrict__ out)
{
    __shared__ __align__(16) short As[128][40];
    __shared__ __align__(16) short Bs[128][40];
    const int tid = threadIdx.x;
    const int lane = tid & 63, wave = tid >> 6;
    const int wm = wave & 1, wn = wave >> 1;
    const int l15 = lane & 15, quad = lane >> 4;
    const int n0 = blockIdx.x * 128, m0 = blockIdx.y * 128;
    const int srow = tid >> 1, skh = (tid & 1) * 16;

    f32x4 zero = {0.f, 0.f, 0.f, 0.f};
    f32x4 acc[4][4];
    #pragma unroll
    for (int i = 0; i < 4; ++i)
        #pragma unroll
        for (int j = 0; j < 4; ++j) acc[i][j] = zero;

    for (int k0 = 0; k0 < DMODEL; k0 += 32) {
        const short* ap = Ab + (size_t)(m0 + srow) * DMODEL + k0 + skh;
        const short* bp = Wt + (size_t)(n0 + srow) * DMODEL + k0 + skh;
        bf16x8 a0 = *(const bf16x8*)ap, a1 = *(const bf16x8*)(ap + 8);
        bf16x8 b0 = *(const bf16x8*)bp, b1 = *(const bf16x8*)(bp + 8);
        __syncthreads();
        *(bf16x8*)&As[srow][skh] = a0; *(bf16x8*)&As[srow][skh + 8] = a1;
        *(bf16x8*)&Bs[srow][skh] = b0; *(bf16x8*)&Bs[srow][skh + 8] = b1;
        __syncthreads();
        bf16x8 af[4], bfr[4];
        #pragma unroll
        for (int i = 0; i < 4; ++i)
            af[i] = *(const bf16x8*)&As[wm * 64 + i * 16 + l15][quad * 8];
        #pragma unroll
        for (int j = 0; j < 4; ++j)
            bfr[j] = *(const bf16x8*)&Bs[wn * 64 + j * 16 + l15][quad * 8];
        #pragma unroll
        for (int i = 0; i < 4; ++i)
            #pragma unroll
            for (int j = 0; j < 4; ++j)
                acc[i][j] = __builtin_amdgcn_mfma_f32_16x16x32_bf16(af[i], bfr[j], acc[i][j], 0, 0, 0);
    }

    #pragma unroll
    for (int j = 0; j < 4; ++j) {
        const int n = n0 + wn * 64 + j * 16 + l15;
        const float bv = bias[n];
        #pragma unroll
        for (int i = 0; i < 4; ++i)
            #pragma unroll
            for (int r = 0; r < 4; ++r) {
                const int m = m0 + wm * 64 + i * 16 + quad * 4 + r;
                out[(size_t)m * DMODEL + n] = acc[i][j][r] + bv;
            }
    }
}

// ---------------------------------------------------------------------------
extern "C" void kernel_launch(void* const* d_in, const int* in_sizes, int n_in,
                              void* d_out, int out_size, void* d_ws, size_t ws_size,
                              hipStream_t stream) {
    const float* x    = (const float*)d_in[0];
    const float* Wqkv = (const float*)d_in[1];
    const float* bqkv = (const float*)d_in[2];
    const float* Wout = (const float*)d_in[3];
    const float* bout = (const float*)d_in[4];
    float* out = (float*)d_out;

    short* ws = (short*)d_ws;
    short* xb     = ws;                                // 4M elems
    short* wqkv_t = xb + (size_t)4 * 1024 * 1024;      // 3M
    short* wout_t = wqkv_t + (size_t)3 * 1024 * 1024;  // 1M
    short* qd     = wout_t + (size_t)1024 * 1024;      // 4M
    short* kd     = qd + (size_t)4 * 1024 * 1024;      // 4M
    short* vd     = kd + (size_t)4 * 1024 * 1024;      // 4M
    short* vtb    = vd + (size_t)4 * 1024 * 1024;      // 4M
    short* attn   = vtb + (size_t)4 * 1024 * 1024;     // 4M  (total 56 MB)

    convert_kernel<<<(MROWS * DMODEL) / (256 * 8), 256, 0, stream>>>(
        x, xb, MROWS * DMODEL);
    transpose_convert_kernel<<<dim3(NQKV / 32, DMODEL / 32), dim3(32, 8), 0, stream>>>(
        Wqkv, wqkv_t, DMODEL, NQKV);
    transpose_convert_kernel<<<dim3(DMODEL / 32, DMODEL / 32), dim3(32, 8), 0, stream>>>(
        Wout, wout_t, DMODEL, DMODEL);

    qkv_gemm_kernel<<<dim3(NQKV / 128, MROWS / 128), 256, 0, stream>>>(
        xb, wqkv_t, bqkv, qd, kd, vd);

    transpose_v_kernel<<<dim3(SEQ / 64, BATCH * NHEAD), 256, 0, stream>>>(vd, vtb);

    attn_mfma_kernel<<<dim3(16, NHEAD, BATCH), 256, 0, stream>>>(
        qd, kd, vtb, attn);

    out_gemm_kernel<<<dim3(DMODEL / 128, MROWS / 128), 256, 0, stream>>>(
        attn, wout_t, bout, out);
}